// Round 9
// baseline (856.463 us; speedup 1.0000x reference)
//
#include <hip/hip_runtime.h>

#define SG 128
#define C 32
#define NPB 250000
#define BATCH 2
#define M (BATCH * NPB)
#define MP 500032            // M padded to multiple of 64
#define NW (MP / 64)         // 7813 groups of 64 points
#define NK 27
#define NBKT 65536           // {b,x/4,y/4,z/4} buckets

typedef __attribute__((ext_vector_type(4))) float f32x4;
typedef __attribute__((ext_vector_type(8))) short bf16x8;

union frag_u { unsigned u[4]; bf16x8 v; };
struct FragSet { frag_u ah[4], al[4], bh0, bl0, bh1, bl1; };

__device__ __forceinline__ int bucket_key(int b, int x, int y, int z) {
    return (b << 15) | ((x >> 2) << 10) | ((y >> 2) << 5) | (z >> 2);
}

// ---------------- counting sort: histogram ----------------
__global__ void hist_kernel(const int* __restrict__ coords, int* __restrict__ hist) {
    int p = blockIdx.x * blockDim.x + threadIdx.x;
    if (p >= M) return;
    int x = coords[3 * p + 0], y = coords[3 * p + 1], z = coords[3 * p + 2];
    atomicAdd(&hist[bucket_key(p >= NPB, x, y, z)], 1);
}

// ---------------- counting sort: single-block exclusive scan (in place) ------
__global__ __launch_bounds__(256) void scan_kernel(int* __restrict__ h) {
    __shared__ int part[256];
    int t = threadIdx.x;
    int s = 0;
    for (int i = 0; i < 256; i++) s += h[t * 256 + i];
    part[t] = s;
    __syncthreads();
    if (t == 0) {
        int run = 0;
        for (int i = 0; i < 256; i++) { int v = part[i]; part[i] = run; run += v; }
    }
    __syncthreads();
    int run = part[t];
    for (int i = 0; i < 256; i++) { int v = h[t * 256 + i]; h[t * 256 + i] = run; run += v; }
}

// ---------------- counting sort: place; also scatter physical id into grid ---
__global__ void place_kernel(const int* __restrict__ coords, int* __restrict__ h,
                             int* __restrict__ ord, int* __restrict__ gridP) {
    int p = blockIdx.x * blockDim.x + threadIdx.x;
    if (p >= M) return;
    int x = coords[3 * p + 0], y = coords[3 * p + 1], z = coords[3 * p + 2];
    int b = (p >= NPB) ? 1 : 0;
    int j = atomicAdd(&h[bucket_key(b, x, y, z)], 1);
    ord[j] = p;
    gridP[((b * SG + x) * SG + y) * SG + z] = j;
}

// ------- build neighbor table nbT[k][w][lrow][rt] (physical order, int4) -----
__global__ void build_nb_kernel(const int* __restrict__ coords,
                                const int* __restrict__ ord,
                                const int* __restrict__ gridP,
                                int* __restrict__ nbT) {
    int j = blockIdx.x * blockDim.x + threadIdx.x;
    if (j >= MP) return;
    int w = j >> 6, rt = (j >> 4) & 3, lrow = j & 15;
    if (j >= M) {
#pragma unroll
        for (int k = 0; k < NK; k++)
            nbT[((size_t)(k * NW + w) * 16 + lrow) * 4 + rt] = -1;
        return;
    }
    int p = ord[j];
    int x = coords[3 * p + 0], y = coords[3 * p + 1], z = coords[3 * p + 2];
    int base = (p >= NPB) ? SG * SG * SG : 0;
#pragma unroll
    for (int k = 0; k < NK; k++) {
        int nx = x + k / 9 - 1;
        int ny = y + (k / 3) % 3 - 1;
        int nz = z + (k % 3) - 1;
        int idx = -1;
        if ((unsigned)nx < SG && (unsigned)ny < SG && (unsigned)nz < SG)
            idx = gridP[base + (nx * SG + ny) * SG + nz];
        nbT[((size_t)(k * NW + w) * 16 + lrow) * 4 + rt] = idx;
    }
}

// ---------------- pack W into MFMA B-fragment layout, split bf16 hi/lo -------
__global__ void prep_w_kernel(const float* __restrict__ W, unsigned short* __restrict__ wpk) {
    int id = blockIdx.x * blockDim.x + threadIdx.x;
    if (id >= NK * 2 * 64) return;
    int l = id & 63, ct = (id >> 6) & 1, k = id >> 7;
    int lrow = l & 15, kg = l >> 4;
    unsigned hw[4], lw[4];
#pragma unroll
    for (int jp = 0; jp < 4; jp++) {
        float v0 = W[k * 1024 + (kg * 8 + 2 * jp + 0) * 32 + ct * 16 + lrow];
        float v1 = W[k * 1024 + (kg * 8 + 2 * jp + 1) * 32 + ct * 16 + lrow];
        unsigned u0 = __float_as_uint(v0), u1 = __float_as_uint(v1);
        hw[jp] = (u0 >> 16) | (u1 & 0xFFFF0000u);
        float h0 = __uint_as_float(u0 & 0xFFFF0000u);
        float h1 = __uint_as_float(u1 & 0xFFFF0000u);
        lw[jp] = (__float_as_uint(v0 - h0) >> 16) | (__float_as_uint(v1 - h1) & 0xFFFF0000u);
    }
    unsigned* dh = (unsigned*)(wpk + k * 2048 + ((ct * 2 + 0) * 64 + l) * 8);
    unsigned* dl = (unsigned*)(wpk + k * 2048 + ((ct * 2 + 1) * 64 + l) * 8);
#pragma unroll
    for (int i = 0; i < 4; i++) { dh[i] = hw[i]; dl[i] = lw[i]; }
}

__device__ __forceinline__ void split1(float v, unsigned short& h, unsigned short& lo) {
    unsigned u = __float_as_uint(v);
    h = (unsigned short)(u >> 16);
    float hf = __uint_as_float(u & 0xFFFF0000u);
    lo = (unsigned short)(__float_as_uint(v - hf) >> 16);
}

// ---------------- split input features -> packed hi|lo rows, PHYSICAL order --
__global__ void split_in_kernel(const float* __restrict__ f, const int* __restrict__ ord,
                                unsigned short* __restrict__ fpk) {
    int id = blockIdx.x * blockDim.x + threadIdx.x;
    if (id >= M * 8) return;
    int j = id >> 3, c4 = id & 7;
    int p = ord[j];
    f32x4 v = *(const f32x4*)&f[p * 32 + c4 * 4];
    ushort4 h, lo;
    split1(v[0], h.x, lo.x);
    split1(v[1], h.y, lo.y);
    split1(v[2], h.z, lo.z);
    split1(v[3], h.w, lo.w);
    *(ushort4*)&fpk[j * 64 + c4 * 4] = h;
    *(ushort4*)&fpk[j * 64 + 32 + c4 * 4] = lo;
}

// ---------------- pipelined conv helpers ----------------
__device__ __forceinline__ void load_AW(FragSet& s, const int4 q,
                                        const unsigned short* __restrict__ fpk,
                                        const unsigned short* __restrict__ zrow,
                                        const unsigned short* __restrict__ wpk,
                                        int k, int l, int ci0) {
    const unsigned short* wb = wpk + (k << 11);
    s.bh0.v = *(const bf16x8*)(wb + ((0 * 64 + l) << 3));
    s.bl0.v = *(const bf16x8*)(wb + ((1 * 64 + l) << 3));
    s.bh1.v = *(const bf16x8*)(wb + ((2 * 64 + l) << 3));
    s.bl1.v = *(const bf16x8*)(wb + ((3 * 64 + l) << 3));
    int nbv[4] = {q.x, q.y, q.z, q.w};
#pragma unroll
    for (int rt = 0; rt < 4; rt++) {
        int idx = nbv[rt];
        const unsigned short* src = (idx >= 0) ? (fpk + (size_t)idx * 64) : zrow;
        s.ah[rt].v = *(const bf16x8*)(src + ci0);
        s.al[rt].v = *(const bf16x8*)(src + ci0 + 32);
    }
}

__device__ __forceinline__ void do_mfma(const FragSet& s, f32x4 (&acc)[4][2]) {
#pragma unroll
    for (int rt = 0; rt < 4; rt++) {
        acc[rt][0] = __builtin_amdgcn_mfma_f32_16x16x32_bf16(s.ah[rt].v, s.bh0.v, acc[rt][0], 0, 0, 0);
        acc[rt][1] = __builtin_amdgcn_mfma_f32_16x16x32_bf16(s.ah[rt].v, s.bh1.v, acc[rt][1], 0, 0, 0);
        acc[rt][0] = __builtin_amdgcn_mfma_f32_16x16x32_bf16(s.ah[rt].v, s.bl0.v, acc[rt][0], 0, 0, 0);
        acc[rt][1] = __builtin_amdgcn_mfma_f32_16x16x32_bf16(s.ah[rt].v, s.bl1.v, acc[rt][1], 0, 0, 0);
        acc[rt][0] = __builtin_amdgcn_mfma_f32_16x16x32_bf16(s.al[rt].v, s.bh0.v, acc[rt][0], 0, 0, 0);
        acc[rt][1] = __builtin_amdgcn_mfma_f32_16x16x32_bf16(s.al[rt].v, s.bh1.v, acc[rt][1], 0, 0, 0);
    }
}

// ------- conv: block = one 64-pt group, 4 waves split the 27 taps 7/7/7/6 ----
// Waves 1-3 spill partial acc to LDS (chunk-major, conflict-free); wave 0
// reduces in fixed order then does the epilogue. Deterministic.
template <bool RELU, bool LAST>
__global__ __launch_bounds__(256, 4) void conv_mfma(
    const unsigned short* __restrict__ fpk,  // [MP][64] packed hi|lo (physical)
    const int* __restrict__ nbT,             // [27][NW][16][4] physical nb ids
    const unsigned short* __restrict__ wpk,  // packed B-frags
    const unsigned short* __restrict__ zrow, // 128 B of zeros
    const int* __restrict__ ord,             // physical -> logical (LAST only)
    unsigned short* __restrict__ opk,        // [MP][64] if !LAST
    float* __restrict__ of32)                // [M][32] if LAST (scattered)
{
    __shared__ f32x4 red[3][8][64];          // 24.6 KB partial accumulators

    const int t = threadIdx.x;
    const int l = t & 63;
    const int wv = t >> 6;                   // tap-partition 0..3
    const int w = blockIdx.x;
    if (w >= NW) return;
    const int wbase = w * 64;
    const int lrow = l & 15, kg = l >> 4, ci0 = kg * 8;

    f32x4 acc[4][2];
#pragma unroll
    for (int rt = 0; rt < 4; rt++)
#pragma unroll
        for (int ct = 0; ct < 2; ct++) acc[rt][ct] = (f32x4){0.f, 0.f, 0.f, 0.f};

    const int kbeg = wv * 7;                 // 0,7,14,21; wv=3 has 6 taps
#define NBQ(K) (*(const int4*)(nbT + ((size_t)((K) * NW + w) * 16 + lrow) * 4))

    int4 q0, q1;
    FragSet A, B;

    q0 = NBQ(kbeg);
    q1 = NBQ(kbeg + 1);
    load_AW(A, q0, fpk, zrow, wpk, kbeg, l, ci0);

#pragma unroll
    for (int i = 0; i < 3; i++) {
        const int k = kbeg + 2 * i;
        const int k2 = (k + 2 > 26) ? 26 : (k + 2);
        const int k3 = (k + 3 > 26) ? 26 : (k + 3);
        q0 = NBQ(k2);
        load_AW(B, q1, fpk, zrow, wpk, k + 1, l, ci0);
        __builtin_amdgcn_sched_barrier(0);
        do_mfma(A, acc);                     // tap k
        __builtin_amdgcn_sched_barrier(0);
        q1 = NBQ(k3);
        load_AW(A, q0, fpk, zrow, wpk, k2, l, ci0);
        __builtin_amdgcn_sched_barrier(0);
        do_mfma(B, acc);                     // tap k+1
        __builtin_amdgcn_sched_barrier(0);
    }
    if (wv < 3) do_mfma(A, acc);             // 7th tap (kbeg+6)
#undef NBQ

    // ---- cross-wave reduction: waves 1-3 spill, wave 0 accumulates ----
    if (wv > 0) {
#pragma unroll
        for (int rt = 0; rt < 4; rt++)
#pragma unroll
            for (int ct = 0; ct < 2; ct++)
                red[wv - 1][rt * 2 + ct][l] = acc[rt][ct];
    }
    __syncthreads();
    if (wv != 0) return;
#pragma unroll
    for (int s = 0; s < 3; s++)
#pragma unroll
        for (int rt = 0; rt < 4; rt++)
#pragma unroll
            for (int ct = 0; ct < 2; ct++)
                acc[rt][ct] += red[s][rt * 2 + ct][l];

    // epilogue (wave 0)
#pragma unroll
    for (int rt = 0; rt < 4; rt++) {
        int rbase = wbase + rt * 16 + 4 * kg;
#pragma unroll
        for (int j = 0; j < 4; j++) {
            int row = rbase + j;
            if (row < M) {
                int orow = LAST ? ord[row] : row;
#pragma unroll
                for (int ct = 0; ct < 2; ct++) {
                    int col = ct * 16 + lrow;
                    float v = acc[rt][ct][j];
                    if (RELU) v = fmaxf(v, 0.f);
                    if (LAST) {
                        of32[orow * 32 + col] = v;
                    } else {
                        unsigned short h, lo;
                        split1(v, h, lo);
                        opk[row * 64 + col] = h;
                        opk[row * 64 + 32 + col] = lo;
                    }
                }
            }
        }
    }
}

extern "C" void kernel_launch(void* const* d_in, const int* in_sizes, int n_in,
                              void* d_out, int out_size, void* d_ws, size_t ws_size,
                              hipStream_t stream) {
    const float* features    = (const float*)d_in[0];
    const int*   coordinates = (const int*)d_in[1];
    const float* W1 = (const float*)d_in[4];
    const float* W2 = (const float*)d_in[5];
    const float* W3 = (const float*)d_in[6];

    char* ws = (char*)d_ws;
    const size_t GRID_BYTES = (size_t)BATCH * SG * SG * SG * 4;   // 16.78 MB
    const size_t NB_BYTES   = (size_t)NK * NW * 16 * 4 * 4;       // 54.0 MB
    const size_t HIST_BYTES = (size_t)NBKT * 4;                   // 256 KB
    const size_t ORD_BYTES  = (size_t)MP * 4;                     // 2.0 MB
    const size_t WPK_BYTES  = (size_t)NK * 2048 * 2;              // 110,592 B
    const size_t Z_BYTES    = 256;

    size_t off = 0;
    int* gridP = (int*)(ws + off); off += GRID_BYTES;
    int* nbT   = (int*)(ws + off); off += NB_BYTES;
    int* hist  = (int*)(ws + off); off += HIST_BYTES;
    int* ord   = (int*)(ws + off); off += ORD_BYTES;
    unsigned short* wpk1 = (unsigned short*)(ws + off); off += WPK_BYTES;
    unsigned short* wpk2 = (unsigned short*)(ws + off); off += WPK_BYTES;
    unsigned short* wpk3 = (unsigned short*)(ws + off); off += WPK_BYTES;
    unsigned short* zrow = (unsigned short*)(ws + off); off += Z_BYTES;
    unsigned short* fpk_a = (unsigned short*)(ws + off); off += (size_t)MP * 64 * 2; // 64 MB
    unsigned short* fpk_b = (unsigned short*)d_out;  // 64 MB, overwritten by final f32 out
    float* out = (float*)d_out;

    hipMemsetAsync(gridP, 0xFF, GRID_BYTES, stream);
    hipMemsetAsync(hist, 0, HIST_BYTES, stream);
    hipMemsetAsync(zrow, 0, Z_BYTES, stream);

    hist_kernel<<<(M + 255) / 256, 256, 0, stream>>>(coordinates, hist);
    scan_kernel<<<1, 256, 0, stream>>>(hist);
    place_kernel<<<(M + 255) / 256, 256, 0, stream>>>(coordinates, hist, ord, gridP);
    build_nb_kernel<<<(MP + 255) / 256, 256, 0, stream>>>(coordinates, ord, gridP, nbT);

    const int PW = NK * 2 * 64;
    prep_w_kernel<<<(PW + 255) / 256, 256, 0, stream>>>(W1, wpk1);
    prep_w_kernel<<<(PW + 255) / 256, 256, 0, stream>>>(W2, wpk2);
    prep_w_kernel<<<(PW + 255) / 256, 256, 0, stream>>>(W3, wpk3);

    split_in_kernel<<<(M * 8 + 255) / 256, 256, 0, stream>>>(features, ord, fpk_a);

    conv_mfma<true,  false><<<NW, 256, 0, stream>>>(fpk_a, nbT, wpk1, zrow, ord, fpk_b, nullptr);
    conv_mfma<true,  false><<<NW, 256, 0, stream>>>(fpk_b, nbT, wpk2, zrow, ord, fpk_a, nullptr);
    conv_mfma<false, true ><<<NW, 256, 0, stream>>>(fpk_a, nbT, wpk3, zrow, ord, nullptr, out);
}

// Round 10
// 490.027 us; speedup vs baseline: 1.7478x; 1.7478x over previous
//
#include <hip/hip_runtime.h>

#define SG 128
#define C 32
#define NPB 250000
#define BATCH 2
#define M (BATCH * NPB)
#define MP 500032            // M padded to multiple of 64
#define NW (MP / 64)         // 7813 groups of 64 points
#define NK 27
#define NBKT 65536           // {b,x/4,y/4,z/4} buckets
#define CAP 256              // max unique neighbor rows per group
#define HSZ 1024             // hash table size (per-block LDS)

typedef __attribute__((ext_vector_type(4))) float f32x4;
typedef __attribute__((ext_vector_type(8))) short bf16x8;

union frag_u { unsigned u[4]; bf16x8 v; };
struct FragSet { frag_u ah[4], al[4], bh0, bl0, bh1, bl1; };

__device__ __forceinline__ int bucket_key(int b, int x, int y, int z) {
    return (b << 15) | ((x >> 2) << 10) | ((y >> 2) << 5) | (z >> 2);
}

// ---------------- counting sort: histogram ----------------
__global__ void hist_kernel(const int* __restrict__ coords, int* __restrict__ hist) {
    int p = blockIdx.x * blockDim.x + threadIdx.x;
    if (p >= M) return;
    int x = coords[3 * p + 0], y = coords[3 * p + 1], z = coords[3 * p + 2];
    atomicAdd(&hist[bucket_key(p >= NPB, x, y, z)], 1);
}

// ---------------- counting sort: single-block exclusive scan (in place) ------
__global__ __launch_bounds__(256) void scan_kernel(int* __restrict__ h) {
    __shared__ int part[256];
    int t = threadIdx.x;
    int s = 0;
    for (int i = 0; i < 256; i++) s += h[t * 256 + i];
    part[t] = s;
    __syncthreads();
    if (t == 0) {
        int run = 0;
        for (int i = 0; i < 256; i++) { int v = part[i]; part[i] = run; run += v; }
    }
    __syncthreads();
    int run = part[t];
    for (int i = 0; i < 256; i++) { int v = h[t * 256 + i]; h[t * 256 + i] = run; run += v; }
}

// ---------------- counting sort: place; also scatter physical id into grid ---
__global__ void place_kernel(const int* __restrict__ coords, int* __restrict__ h,
                             int* __restrict__ ord, int* __restrict__ gridP) {
    int p = blockIdx.x * blockDim.x + threadIdx.x;
    if (p >= M) return;
    int x = coords[3 * p + 0], y = coords[3 * p + 1], z = coords[3 * p + 2];
    int b = (p >= NPB) ? 1 : 0;
    int j = atomicAdd(&h[bucket_key(b, x, y, z)], 1);
    ord[j] = p;
    gridP[((b * SG + x) * SG + y) * SG + z] = j;
}

// ------- fused neighbor-build + dedup: one wave per 64-pt group --------------
// Produces: uniq[w][CAP] unique neighbor physical ids (slot 0 = zero row),
//           ucnt[w], and nbL[k][w][lrow][rt] = 16-bit slot index.
__global__ __launch_bounds__(64) void build_dedup_kernel(
    const int* __restrict__ coords, const int* __restrict__ ord,
    const int* __restrict__ gridP,
    unsigned short* __restrict__ nbL, int* __restrict__ uniq, int* __restrict__ ucnt)
{
    __shared__ int hkey[HSZ];
    __shared__ int hval[HSZ];
    __shared__ int hcnt;
    const int t = threadIdx.x;           // 64 threads = 1 wave
    const int w = blockIdx.x;
    for (int i = t; i < HSZ; i += 64) { hkey[i] = -2; hval[i] = -1; }
    if (t == 0) { hcnt = 1; uniq[w * CAP] = -1; }
    __syncthreads();

    const int j = w * 64 + t;
    int x = 0, y = 0, z = 0, base = 0;
    const bool real = (j < M);
    if (real) {
        int p = ord[j];
        x = coords[3 * p + 0]; y = coords[3 * p + 1]; z = coords[3 * p + 2];
        base = (p >= NPB) ? SG * SG * SG : 0;
    }
    for (int k = 0; k < NK; k++) {
        int id = -1;
        if (real) {
            int nx = x + k / 9 - 1;
            int ny = y + (k / 3) % 3 - 1;
            int nz = z + (k % 3) - 1;
            if ((unsigned)nx < SG && (unsigned)ny < SG && (unsigned)nz < SG)
                id = gridP[base + (nx * SG + ny) * SG + nz];
        }
        int slot = 0;
        if (id >= 0) {
            unsigned h = (((unsigned)id * 2654435761u) >> 20) & (HSZ - 1);
            slot = -1;
            while (slot < 0) {
                int old = atomicCAS(&hkey[h], -2, id);
                bool won = (old == -2);
                int myslot = -1;
                if (won) myslot = atomicAdd(&hcnt, 1);
                if (won) {                       // winner publishes before losers read
                    if (myslot < CAP) { hval[h] = myslot; uniq[w * CAP + myslot] = id; slot = myslot; }
                    else { hval[h] = 0; slot = 0; }   // overflow guard (stat. impossible)
                } else if (old == id) {
                    int v = hval[h];
                    if (v >= 0) slot = v;        // else retry same h
                } else {
                    h = (h + 1) & (HSZ - 1);
                }
            }
        }
        nbL[((size_t)(k * NW + w) * 16 + (t & 15)) * 4 + (t >> 4)] = (unsigned short)slot;
    }
    __syncthreads();
    if (t == 0) ucnt[w] = (hcnt < CAP) ? hcnt : CAP;
}

// ---------------- pack W into MFMA B-fragment layout, split bf16 hi/lo -------
__global__ void prep_w_kernel(const float* __restrict__ W, unsigned short* __restrict__ wpk) {
    int id = blockIdx.x * blockDim.x + threadIdx.x;
    if (id >= NK * 2 * 64) return;
    int l = id & 63, ct = (id >> 6) & 1, k = id >> 7;
    int lrow = l & 15, kg = l >> 4;
    unsigned hw[4], lw[4];
#pragma unroll
    for (int jp = 0; jp < 4; jp++) {
        float v0 = W[k * 1024 + (kg * 8 + 2 * jp + 0) * 32 + ct * 16 + lrow];
        float v1 = W[k * 1024 + (kg * 8 + 2 * jp + 1) * 32 + ct * 16 + lrow];
        unsigned u0 = __float_as_uint(v0), u1 = __float_as_uint(v1);
        hw[jp] = (u0 >> 16) | (u1 & 0xFFFF0000u);
        float h0 = __uint_as_float(u0 & 0xFFFF0000u);
        float h1 = __uint_as_float(u1 & 0xFFFF0000u);
        lw[jp] = (__float_as_uint(v0 - h0) >> 16) | (__float_as_uint(v1 - h1) & 0xFFFF0000u);
    }
    unsigned* dh = (unsigned*)(wpk + k * 2048 + ((ct * 2 + 0) * 64 + l) * 8);
    unsigned* dl = (unsigned*)(wpk + k * 2048 + ((ct * 2 + 1) * 64 + l) * 8);
#pragma unroll
    for (int i = 0; i < 4; i++) { dh[i] = hw[i]; dl[i] = lw[i]; }
}

__device__ __forceinline__ void split1(float v, unsigned short& h, unsigned short& lo) {
    unsigned u = __float_as_uint(v);
    h = (unsigned short)(u >> 16);
    float hf = __uint_as_float(u & 0xFFFF0000u);
    lo = (unsigned short)(__float_as_uint(v - hf) >> 16);
}

// ---------------- split input features -> packed hi|lo rows, PHYSICAL order --
__global__ void split_in_kernel(const float* __restrict__ f, const int* __restrict__ ord,
                                unsigned short* __restrict__ fpk) {
    int id = blockIdx.x * blockDim.x + threadIdx.x;
    if (id >= M * 8) return;
    int j = id >> 3, c4 = id & 7;
    int p = ord[j];
    f32x4 v = *(const f32x4*)&f[p * 32 + c4 * 4];
    ushort4 h, lo;
    split1(v[0], h.x, lo.x);
    split1(v[1], h.y, lo.y);
    split1(v[2], h.z, lo.z);
    split1(v[3], h.w, lo.w);
    *(ushort4*)&fpk[j * 64 + c4 * 4] = h;
    *(ushort4*)&fpk[j * 64 + 32 + c4 * 4] = lo;
}

// ---------------- conv helpers ----------------
// LDS row r (128 B): chunk c (16 B) stored at physical chunk c ^ (r&7).
__device__ __forceinline__ void load_AW(FragSet& s, ushort4 q, const char* __restrict__ sm,
                                        const unsigned short* __restrict__ wpk,
                                        int k, int l, int kg) {
    const unsigned short* wb = wpk + (k << 11);
    s.bh0.v = *(const bf16x8*)(wb + ((0 * 64 + l) << 3));
    s.bl0.v = *(const bf16x8*)(wb + ((1 * 64 + l) << 3));
    s.bh1.v = *(const bf16x8*)(wb + ((2 * 64 + l) << 3));
    s.bl1.v = *(const bf16x8*)(wb + ((3 * 64 + l) << 3));
    int rows[4] = {q.x, q.y, q.z, q.w};
#pragma unroll
    for (int rt = 0; rt < 4; rt++) {
        int r = rows[rt];
        const char* base = sm + (r << 7);
        int sw = (r & 7) << 4;
        s.ah[rt].v = *(const bf16x8*)(base + ((kg << 4) ^ sw));
        s.al[rt].v = *(const bf16x8*)(base + (((kg + 4) << 4) ^ sw));
    }
}

__device__ __forceinline__ void do_mfma(const FragSet& s, f32x4 (&acc)[4][2]) {
#pragma unroll
    for (int rt = 0; rt < 4; rt++) {
        acc[rt][0] = __builtin_amdgcn_mfma_f32_16x16x32_bf16(s.ah[rt].v, s.bh0.v, acc[rt][0], 0, 0, 0);
        acc[rt][1] = __builtin_amdgcn_mfma_f32_16x16x32_bf16(s.ah[rt].v, s.bh1.v, acc[rt][1], 0, 0, 0);
        acc[rt][0] = __builtin_amdgcn_mfma_f32_16x16x32_bf16(s.ah[rt].v, s.bl0.v, acc[rt][0], 0, 0, 0);
        acc[rt][1] = __builtin_amdgcn_mfma_f32_16x16x32_bf16(s.ah[rt].v, s.bl1.v, acc[rt][1], 0, 0, 0);
        acc[rt][0] = __builtin_amdgcn_mfma_f32_16x16x32_bf16(s.al[rt].v, s.bh0.v, acc[rt][0], 0, 0, 0);
        acc[rt][1] = __builtin_amdgcn_mfma_f32_16x16x32_bf16(s.al[rt].v, s.bh1.v, acc[rt][1], 0, 0, 0);
    }
}

// ------- conv: block = 2 waves on one 64-pt group; LDS-staged neighborhood ---
// Stage cnt unique rows once into 32 KB LDS; wave 0 taps [0,14), wave 1 [14,27);
// 2-deep pipelined MFMA loop reads A-frags from LDS; reduce reuses staging LDS.
template <bool RELU, bool LAST>
__global__ __launch_bounds__(128, 2) void conv_mfma(
    const unsigned short* __restrict__ fpk,  // [MP][64] packed hi|lo (physical)
    const unsigned short* __restrict__ nbL,  // [27][NW][16][4] slot indices
    const int* __restrict__ uniq,            // [NW][CAP] physical row ids
    const int* __restrict__ ucnt,            // [NW]
    const unsigned short* __restrict__ wpk,  // packed B-frags
    const int* __restrict__ ord,             // physical -> logical (LAST only)
    unsigned short* __restrict__ opk,        // [MP][64] if !LAST
    float* __restrict__ of32)                // [M][32] if LAST (scattered)
{
    __shared__ int4 smem4[CAP * 8];          // 32 KB staged rows (+ reduce reuse)
    char* sm = (char*)smem4;

    const int t = threadIdx.x;
    const int w = blockIdx.x;
    const int wbase = w * 64;

    // ---- stage unique neighbor rows (both waves) ----
    const int cnt = ucnt[w];
    {
        const int c = t & 7;
        for (int r = t >> 3; r < cnt; r += 16) {
            int id = uniq[w * CAP + r];
            int4 v = {0, 0, 0, 0};
            if (id >= 0) v = *(const int4*)(fpk + (size_t)id * 64 + c * 8);
            *(int4*)(sm + (r << 7) + (((c ^ (r & 7))) << 4)) = v;
        }
    }
    __syncthreads();

    const int l = t & 63;
    const int wv = t >> 6;                   // 0 or 1
    const int lrow = l & 15, kg = l >> 4;

    f32x4 acc[4][2];
#pragma unroll
    for (int rt = 0; rt < 4; rt++)
#pragma unroll
        for (int ct = 0; ct < 2; ct++) acc[rt][ct] = (f32x4){0.f, 0.f, 0.f, 0.f};

    const int kbeg = wv ? 14 : 0;
    const int kend = wv ? 27 : 14;

#define LDQ(K) (*(const ushort4*)(nbL + ((size_t)((K) * NW + w) * 16 + lrow) * 4))

    int k = kbeg;
    ushort4 q0 = LDQ(k);
    ushort4 q1 = LDQ(k + 1 < kend ? k + 1 : k);
    FragSet A, B;
    load_AW(A, q0, sm, wpk, k, l, kg);

#pragma unroll 1
    while (k + 2 <= kend) {
        int ka = (k + 2 < kend) ? k + 2 : k;
        q0 = LDQ(ka);
        load_AW(B, q1, sm, wpk, k + 1, l, kg);
        __builtin_amdgcn_sched_barrier(0);
        do_mfma(A, acc);                     // tap k
        __builtin_amdgcn_sched_barrier(0);
        int kb = (k + 3 < kend) ? k + 3 : k;
        q1 = LDQ(kb);
        load_AW(A, q0, sm, wpk, ka, l, kg);
        __builtin_amdgcn_sched_barrier(0);
        do_mfma(B, acc);                     // tap k+1
        __builtin_amdgcn_sched_barrier(0);
        k += 2;
    }
    if (k < kend) do_mfma(A, acc);           // odd tail (wave 1)
#undef LDQ

    // ---- cross-wave reduction (reuse staging LDS after all taps done) ----
    __syncthreads();
    f32x4* red = (f32x4*)sm;
    if (wv == 1) {
#pragma unroll
        for (int rt = 0; rt < 4; rt++)
#pragma unroll
            for (int ct = 0; ct < 2; ct++)
                red[(rt * 2 + ct) * 64 + l] = acc[rt][ct];
    }
    __syncthreads();
    if (wv != 0) return;
#pragma unroll
    for (int rt = 0; rt < 4; rt++)
#pragma unroll
        for (int ct = 0; ct < 2; ct++)
            acc[rt][ct] += red[(rt * 2 + ct) * 64 + l];

    // ---- epilogue (wave 0) ----
#pragma unroll
    for (int rt = 0; rt < 4; rt++) {
        int rbase = wbase + rt * 16 + 4 * kg;
#pragma unroll
        for (int j = 0; j < 4; j++) {
            int row = rbase + j;
            if (row < M) {
                int orow = LAST ? ord[row] : row;
#pragma unroll
                for (int ct = 0; ct < 2; ct++) {
                    int col = ct * 16 + lrow;
                    float v = acc[rt][ct][j];
                    if (RELU) v = fmaxf(v, 0.f);
                    if (LAST) {
                        of32[orow * 32 + col] = v;
                    } else {
                        unsigned short h, lo;
                        split1(v, h, lo);
                        opk[row * 64 + col] = h;
                        opk[row * 64 + 32 + col] = lo;
                    }
                }
            }
        }
    }
}

extern "C" void kernel_launch(void* const* d_in, const int* in_sizes, int n_in,
                              void* d_out, int out_size, void* d_ws, size_t ws_size,
                              hipStream_t stream) {
    const float* features    = (const float*)d_in[0];
    const int*   coordinates = (const int*)d_in[1];
    const float* W1 = (const float*)d_in[4];
    const float* W2 = (const float*)d_in[5];
    const float* W3 = (const float*)d_in[6];

    char* ws = (char*)d_ws;
    const size_t GRID_BYTES = (size_t)BATCH * SG * SG * SG * 4;   // 16.78 MB
    const size_t NBL_BYTES  = (size_t)NK * NW * 64 * 2;           // 27.0 MB
    const size_t UNIQ_BYTES = (size_t)NW * CAP * 4;               // 8.0 MB
    const size_t UCNT_BYTES = (size_t)NW * 4;                     // 31 KB
    const size_t HIST_BYTES = (size_t)NBKT * 4;                   // 256 KB
    const size_t ORD_BYTES  = (size_t)MP * 4;                     // 2.0 MB
    const size_t WPK_BYTES  = (size_t)NK * 2048 * 2;              // 110,592 B

    size_t off = 0;
    int* gridP = (int*)(ws + off); off += GRID_BYTES;
    unsigned short* nbL = (unsigned short*)(ws + off); off += NBL_BYTES;
    int* uniq  = (int*)(ws + off); off += UNIQ_BYTES;
    int* ucnt  = (int*)(ws + off); off += UCNT_BYTES;
    int* hist  = (int*)(ws + off); off += HIST_BYTES;
    int* ord   = (int*)(ws + off); off += ORD_BYTES;
    unsigned short* wpk1 = (unsigned short*)(ws + off); off += WPK_BYTES;
    unsigned short* wpk2 = (unsigned short*)(ws + off); off += WPK_BYTES;
    unsigned short* wpk3 = (unsigned short*)(ws + off); off += WPK_BYTES;
    unsigned short* fpk_a = (unsigned short*)(ws + off); off += (size_t)MP * 64 * 2; // 64 MB
    unsigned short* fpk_b = (unsigned short*)d_out;  // 64 MB, overwritten by final f32 out
    float* out = (float*)d_out;

    hipMemsetAsync(gridP, 0xFF, GRID_BYTES, stream);
    hipMemsetAsync(hist, 0, HIST_BYTES, stream);

    hist_kernel<<<(M + 255) / 256, 256, 0, stream>>>(coordinates, hist);
    scan_kernel<<<1, 256, 0, stream>>>(hist);
    place_kernel<<<(M + 255) / 256, 256, 0, stream>>>(coordinates, hist, ord, gridP);
    build_dedup_kernel<<<NW, 64, 0, stream>>>(coordinates, ord, gridP, nbL, uniq, ucnt);

    const int PW = NK * 2 * 64;
    prep_w_kernel<<<(PW + 255) / 256, 256, 0, stream>>>(W1, wpk1);
    prep_w_kernel<<<(PW + 255) / 256, 256, 0, stream>>>(W2, wpk2);
    prep_w_kernel<<<(PW + 255) / 256, 256, 0, stream>>>(W3, wpk3);

    split_in_kernel<<<(M * 8 + 255) / 256, 256, 0, stream>>>(features, ord, fpk_a);

    conv_mfma<true,  false><<<NW, 128, 0, stream>>>(fpk_a, nbL, uniq, ucnt, wpk1, ord, fpk_b, nullptr);
    conv_mfma<true,  false><<<NW, 128, 0, stream>>>(fpk_b, nbL, uniq, ucnt, wpk2, ord, fpk_a, nullptr);
    conv_mfma<false, true ><<<NW, 128, 0, stream>>>(fpk_a, nbL, uniq, ucnt, wpk3, ord, nullptr, out);
}